// Round 11
// baseline (2068.750 us; speedup 1.0000x reference)
//
#include <hip/hip_runtime.h>
#include <math.h>

#define DIM    1024
#define HEADS  16
#define HDIM   64
#define HIDDEN 4096
#define BATCH  4
#define SEQ    1024
#define ROWS   (BATCH * SEQ)   // 4096
#define NBLK   1024            // persistent grid: 4 blocks/CU x 256 CU

typedef short s16x8 __attribute__((ext_vector_type(8)));
typedef float f32x4 __attribute__((ext_vector_type(4)));

// ---- bf16 helpers ----
__device__ __forceinline__ float blo(unsigned int u) {
    union { unsigned int i; float f; } x; x.i = u << 16; return x.f;
}
__device__ __forceinline__ float bhi(unsigned int u) {
    union { unsigned int i; float f; } x; x.i = u & 0xffff0000u; return x.f;
}
__device__ __forceinline__ unsigned short f2b(float f) {   // round-to-nearest-even
    union { float f; unsigned int i; } x; x.f = f;
    unsigned int r = x.i + 0x7fffu + ((x.i >> 16) & 1u);
    return (unsigned short)(r >> 16);
}

// ---- fast exact-GELU: branchless A&S 7.1.26 erf, max |err| ~1.5e-7 ----
__device__ __forceinline__ float gelu_f(float x) {
    float z  = fabsf(x) * 0.70710678118f;
    float t  = __builtin_amdgcn_rcpf(__builtin_fmaf(0.3275911f, z, 1.0f));
    float p  = ((((1.061405429f * t - 1.453152027f) * t + 1.421413741f) * t
                 - 0.284496736f) * t + 0.254829592f) * t;
    float e  = exp2f(-0.72134752f * x * x);
    float w  = 0.5f * p * e;
    float phi = (x >= 0.0f) ? (1.0f - w) : w;
    return x * phi;
}

// ---- TILED operand layout: chunk = 16 rows x 32 k, 1KB contiguous, MFMA lane order ----
__device__ __forceinline__ size_t tidx(int row, int k, int Kdim) {
    return ((size_t)(row >> 4) * (Kdim >> 5) + (k >> 5)) * 512
         + (size_t)(((k & 31) >> 3) * 128 + (row & 15) * 8 + (k & 7));
}

// ---- async global->LDS, 16B/lane ----
__device__ __forceinline__ void gload_lds16(const void* g, void* l) {
    __builtin_amdgcn_global_load_lds(
        (const __attribute__((address_space(1))) unsigned int*)g,
        (__attribute__((address_space(3))) unsigned int*)l, 16, 0, 0);
}

// ---- grid barrier: count + generation, device scope (cross-XCD via threadfence) ----
// g_bar zero-initialized at module load; cnt returns to 0 after each barrier and gen
// is monotonic, so no reset needed across graph iterations.
__device__ unsigned int g_bar[2];

__device__ __forceinline__ void gbar() {
    __syncthreads();
    if (threadIdx.x == 0) {
        __threadfence();   // release: make my phase writes visible device-wide
        unsigned int g = __hip_atomic_load(&g_bar[1], __ATOMIC_RELAXED, __HIP_MEMORY_SCOPE_AGENT);
        unsigned int a = __hip_atomic_fetch_add(&g_bar[0], 1u, __ATOMIC_ACQ_REL, __HIP_MEMORY_SCOPE_AGENT);
        if (a == NBLK - 1) {
            __hip_atomic_store(&g_bar[0], 0u, __ATOMIC_RELAXED, __HIP_MEMORY_SCOPE_AGENT);
            __hip_atomic_fetch_add(&g_bar[1], 1u, __ATOMIC_RELEASE, __HIP_MEMORY_SCOPE_AGENT);
        } else {
            while (__hip_atomic_load(&g_bar[1], __ATOMIC_ACQUIRE, __HIP_MEMORY_SCOPE_AGENT) == g)
                __builtin_amdgcn_s_sleep(8);
        }
        __threadfence();   // acquire: invalidate stale cached lines before next phase reads
    }
    __syncthreads();
}

// =================== phase bodies (verbatim R10 kernels, blockIdx -> params) ===================

// ---- prep unit: u < ROWS -> LN row; else wconv tile ----
__device__ void prep_unit(int u, char* SH,
                          const float* x, const float* g, const float* b,
                          unsigned short* lnout,
                          const float* qkv_w, unsigned short* wT_qkv,
                          const float* proj_w, unsigned short* wT_proj,
                          const float* fc1_w, unsigned short* wT_fc1,
                          const float* fc2_w, unsigned short* wT_fc2) {
    const int t = threadIdx.x;
    float* red1 = (float*)SH;            // 256 f32
    float* red2 = red1 + 256;            // 256 f32
    unsigned short* T = (unsigned short*)(SH + 2048);   // [64][68]
    __syncthreads();                     // protect SH reuse across units/phases

    if (u < ROWS) {
        int row = u;
        const float* xr = x + (size_t)row * DIM;
        float4 v = *((const float4*)(xr + t * 4));
        float s  = v.x + v.y + v.z + v.w;
        float ss = v.x * v.x + v.y * v.y + v.z * v.z + v.w * v.w;
        red1[t] = s; red2[t] = ss;
        __syncthreads();
        for (int off = 128; off > 0; off >>= 1) {
            if (t < off) { red1[t] += red1[t + off]; red2[t] += red2[t + off]; }
            __syncthreads();
        }
        float mu   = red1[0] * (1.0f / DIM);
        float var  = red2[0] * (1.0f / DIM) - mu * mu;
        float rstd = rsqrtf(var + 1e-5f);
        float4 gv = *((const float4*)(g + t * 4));
        float4 bv = *((const float4*)(b + t * 4));
        ushort4 o;
        o.x = f2b((v.x - mu) * rstd * gv.x + bv.x);
        o.y = f2b((v.y - mu) * rstd * gv.y + bv.y);
        o.z = f2b((v.z - mu) * rstd * gv.z + bv.z);
        o.w = f2b((v.w - mu) * rstd * gv.w + bv.w);
        *((ushort4*)(lnout + tidx(row, t * 4, DIM))) = o;
    } else {
        int tt = u - ROWS;
        const float* W; unsigned short* Wt; int K, N, bx, by;
        if (tt < 768) {
            W = qkv_w; Wt = wT_qkv; K = DIM; N = 3 * DIM; bx = tt % 48; by = tt / 48;
        } else if (tt < 768 + 256) {
            tt -= 768;
            W = proj_w; Wt = wT_proj; K = DIM; N = DIM; bx = tt % 16; by = tt / 16;
        } else if (tt < 768 + 256 + 1024) {
            tt -= 768 + 256;
            W = fc1_w; Wt = wT_fc1; K = DIM; N = HIDDEN; bx = tt % 64; by = tt / 64;
        } else {
            tt -= 768 + 256 + 1024;
            W = fc2_w; Wt = wT_fc2; K = HIDDEN; N = DIM; bx = tt % 16; by = tt / 16;
        }
        int n0 = bx * 64, k0 = by * 64;
        int cr = t >> 4;
        int cc = (t & 15) * 4;
        #pragma unroll
        for (int r = 0; r < 4; ++r) {
            int kk = cr + 16 * r;
            float4 v = *((const float4*)(W + (size_t)(k0 + kk) * N + n0 + cc));
            T[(cc + 0) * 68 + kk] = f2b(v.x);
            T[(cc + 1) * 68 + kk] = f2b(v.y);
            T[(cc + 2) * 68 + kk] = f2b(v.z);
            T[(cc + 3) * 68 + kk] = f2b(v.w);
        }
        __syncthreads();
        {
            int nn = t >> 2;
            int kg = (t & 3) * 16;
            #pragma unroll
            for (int p = 0; p < 2; ++p) {
                int k8 = kg + p * 8;
                ushort4 lo = *((ushort4*)&T[nn * 68 + k8]);
                ushort4 hi = *((ushort4*)&T[nn * 68 + k8 + 4]);
                unsigned short* dst = Wt + tidx(n0 + nn, k0 + k8, K);
                *((ushort4*)dst)       = lo;
                *((ushort4*)(dst + 4)) = hi;
            }
        }
    }
}

// ---- reduce_ln unit (one row): x1 = x + proj_b + p0 + p1 -> xout; LN2 -> lnout ----
__device__ void reduce_ln_unit(int row, char* SH,
                               const unsigned short* p0, const unsigned short* p1,
                               const float* x, const float* bias,
                               const float* g, const float* b,
                               float* xout, unsigned short* lnout) {
    const int t = threadIdx.x;
    float* red1 = (float*)SH;
    float* red2 = red1 + 256;
    __syncthreads();
    size_t i = (size_t)row * DIM + t * 4;
    float4 xv = *((const float4*)(x + i));
    float4 bi = *((const float4*)(bias + t * 4));
    uint2 w0 = *((const uint2*)(p0 + i));
    uint2 w1 = *((const uint2*)(p1 + i));
    float4 v;
    v.x = xv.x + bi.x + blo(w0.x) + blo(w1.x);
    v.y = xv.y + bi.y + bhi(w0.x) + bhi(w1.x);
    v.z = xv.z + bi.z + blo(w0.y) + blo(w1.y);
    v.w = xv.w + bi.w + bhi(w0.y) + bhi(w1.y);
    *((float4*)(xout + i)) = v;

    float s  = v.x + v.y + v.z + v.w;
    float ss = v.x * v.x + v.y * v.y + v.z * v.z + v.w * v.w;
    red1[t] = s; red2[t] = ss;
    __syncthreads();
    for (int off = 128; off > 0; off >>= 1) {
        if (t < off) { red1[t] += red1[t + off]; red2[t] += red2[t + off]; }
        __syncthreads();
    }
    float mu   = red1[0] * (1.0f / DIM);
    float var  = red2[0] * (1.0f / DIM) - mu * mu;
    float rstd = rsqrtf(var + 1e-5f);
    float4 gv = *((const float4*)(g + t * 4));
    float4 bv = *((const float4*)(b + t * 4));
    ushort4 o;
    o.x = f2b((v.x - mu) * rstd * gv.x + bv.x);
    o.y = f2b((v.y - mu) * rstd * gv.y + bv.y);
    o.z = f2b((v.z - mu) * rstd * gv.z + bv.z);
    o.w = f2b((v.w - mu) * rstd * gv.w + bv.w);
    *((ushort4*)(lnout + tidx(row, t * 4, DIM))) = o;
}

// ---- reduce unit: out = x + bias + sum_s partial_s (2048 units) ----
__device__ void reduce_unit(int u,
                            const unsigned short* p0, const unsigned short* p1,
                            const unsigned short* p2, const unsigned short* p3,
                            const float* x, const float* bias, float* out) {
    int i = (u * 256 + threadIdx.x) * 8;
    int col = i & (DIM - 1);
    float4 b0 = *((const float4*)(bias + col));
    float4 b1 = *((const float4*)(bias + col + 4));
    float4 x0 = *((const float4*)(x + i));
    float4 x1 = *((const float4*)(x + i + 4));
    float a[8] = {x0.x + b0.x, x0.y + b0.y, x0.z + b0.z, x0.w + b0.w,
                  x1.x + b1.x, x1.y + b1.y, x1.z + b1.z, x1.w + b1.w};
    const unsigned short* ps[4] = {p0, p1, p2, p3};
    #pragma unroll
    for (int s = 0; s < 4; ++s) {
        uint4 w = *((const uint4*)(ps[s] + i));
        a[0] += blo(w.x); a[1] += bhi(w.x);
        a[2] += blo(w.y); a[3] += bhi(w.y);
        a[4] += blo(w.z); a[5] += bhi(w.z);
        a[6] += blo(w.w); a[7] += bhi(w.w);
    }
    *((float4*)(out + i))     = make_float4(a[0], a[1], a[2], a[3]);
    *((float4*)(out + i + 4)) = make_float4(a[4], a[5], a[6], a[7]);
}

// ---- GEMM tile (128x128, dbuf @ BK=32) — R10 body, ids from params ----
__device__ void gemm_tile(const unsigned short* A, const unsigned short* Bt,
                          const float* bias, void* Cout, unsigned short* vt,
                          unsigned short* p0, unsigned short* p1,
                          unsigned short* p2, unsigned short* p3,
                          int N, int K, int Ksplit, int fuse,
                          int lin, int mt, int ntl, int z, char* SH) {
    short* Asm = (short*)SH;            // 2 x 4096 shorts
    short* Bsm = (short*)(SH + 16384);  // 2 x 4096 shorts

    const int tid  = threadIdx.x;
    const int lane = tid & 63;
    const int wave = tid >> 6;
    const int wy = wave >> 1, wx = wave & 1;
    const int lr = lane & 15;
    const int lq = lane >> 4;

    int m_t, n_t;
    {
        const int G = 8;
        if (ntl > G) {
            int gsz = mt * G;
            int grp = lin / gsz;
            int rem = lin - grp * gsz;
            m_t = rem % mt;
            n_t = grp * G + rem / mt;
        } else { m_t = lin % mt; n_t = lin / mt; }
    }
    const int m0 = m_t * 128, n0 = n_t * 128;
    const int kbase = z * Ksplit;
    const int kch = K >> 5;

    f32x4 acc[4][4];
    #pragma unroll
    for (int i = 0; i < 4; ++i)
        #pragma unroll
        for (int j = 0; j < 4; ++j)
            acc[i][j] = (f32x4){0.f, 0.f, 0.f, 0.f};

    const unsigned short* ag[2]; const unsigned short* bg[2];
    #pragma unroll
    for (int j = 0; j < 2; ++j) {
        int rc = wave * 2 + j;
        ag[j] = A  + ((size_t)((m0 >> 4) + rc) * kch + (kbase >> 5)) * 512 + lane * 8;
        bg[j] = Bt + ((size_t)((n0 >> 4) + rc) * kch + (kbase >> 5)) * 512 + lane * 8;
    }

#define STAGE(buf) { \
    _Pragma("unroll") for (int j_ = 0; j_ < 2; ++j_) { \
        gload_lds16(ag[j_], &Asm[(buf) * 4096 + (wave * 2 + j_) * 512]); \
        gload_lds16(bg[j_], &Bsm[(buf) * 4096 + (wave * 2 + j_) * 512]); \
        ag[j_] += 512; bg[j_] += 512; \
    } }
#define COMPUTE(buf) { \
    s16x8 af[4], bf[4]; \
    _Pragma("unroll") for (int i_ = 0; i_ < 4; ++i_) \
        af[i_] = *((const s16x8*)&Asm[(buf) * 4096 + (wy * 4 + i_) * 512 + lane * 8]); \
    _Pragma("unroll") for (int j_ = 0; j_ < 4; ++j_) \
        bf[j_] = *((const s16x8*)&Bsm[(buf) * 4096 + (wx * 4 + j_) * 512 + lane * 8]); \
    _Pragma("unroll") for (int i_ = 0; i_ < 4; ++i_) \
        _Pragma("unroll") for (int j_ = 0; j_ < 4; ++j_) \
            acc[i_][j_] = __builtin_amdgcn_mfma_f32_16x16x32_bf16(af[i_], bf[j_], acc[i_][j_], 0, 0, 0); \
    }

    __syncthreads();               // SH handoff from previous phase
    STAGE(0);
    __syncthreads();
    for (int k0 = 0; k0 < Ksplit; k0 += 64) {
        STAGE(1);
        COMPUTE(0);
        __syncthreads();
        if (k0 + 64 < Ksplit) STAGE(0);
        COMPUTE(1);
        __syncthreads();
    }
#undef STAGE
#undef COMPUTE

    short* Wl = (wave < 2 ? Asm : Bsm) + (wave & 1) * 4096;

    if (fuse == 0 && vt && (n0 + wx * 64) >= 2 * DIM) {
        int b_ = (m0 + wy * 64) >> 10;
        int tok0 = (m0 + wy * 64) & 1023;
        int h_ = (n0 + wx * 64 - 2 * DIM) >> 6;
        #pragma unroll
        for (int j = 0; j < 4; ++j) {
            float bi = bias[n0 + wx * 64 + j * 16 + lr];
            #pragma unroll
            for (int i = 0; i < 4; ++i) {
                #pragma unroll
                for (int r = 0; r < 4; ++r) {
                    float val = acc[i][j][r] + bi;
                    int tl = i * 16 + lq * 4 + r;
                    int c  = j * 2 + (i >> 1);
                    int pos = ((tl & 31) >> 3) * 128 + lr * 8 + (tl & 7);
                    Wl[c * 512 + pos] = (short)f2b(val);
                }
            }
        }
        unsigned short* vbase = vt + (size_t)(b_ * 16 + h_) * 65536;
        #pragma unroll
        for (int c = 0; c < 8; ++c) {
            s16x8 v = *((const s16x8*)&Wl[c * 512 + lane * 8]);
            size_t off = ((size_t)(c >> 1) * 32 + (tok0 >> 5) + (c & 1)) * 512 + lane * 8;
            *((s16x8*)&vbase[off]) = v;
        }
    } else if (fuse == 3) {
        #pragma unroll
        for (int j = 0; j < 4; ++j) {
            #pragma unroll
            for (int i = 0; i < 4; ++i) {
                #pragma unroll
                for (int r = 0; r < 4; ++r) {
                    int rowL = i * 16 + lq * 4 + r;
                    int colL = (j * 16 + lr) ^ ((rowL & 7) << 3);
                    Wl[rowL * 64 + colL] = (short)f2b(acc[i][j][r]);
                }
            }
        }
        unsigned short* P = (z == 0) ? p0 : (z == 1) ? p1 : (z == 2) ? p2 : p3;
        unsigned short* Prow = P + (size_t)(m0 + wy * 64 + lane) * N + n0 + wx * 64;
        #pragma unroll
        for (int c = 0; c < 8; ++c) {
            int colr = (c * 8) ^ ((lane & 7) << 3);
            s16x8 v = *((const s16x8*)&Wl[lane * 64 + colr]);
            *((s16x8*)&Prow[c * 8]) = v;
        }
    } else {
        #pragma unroll
        for (int j = 0; j < 4; ++j) {
            float bi = bias[n0 + wx * 64 + j * 16 + lr];
            #pragma unroll
            for (int i = 0; i < 4; ++i) {
                #pragma unroll
                for (int r = 0; r < 4; ++r) {
                    float val = acc[i][j][r] + bi;
                    if (fuse == 1) val = gelu_f(val);
                    int colL = (j & 1) * 16 + lr;
                    int hi = colL >> 3;
                    int pos = hi * 128 + (lq * 4 + r) * 8 + (lr & 7);
                    pos ^= ((pos >> 7) & 3) << 3;
                    Wl[(i * 2 + (j >> 1)) * 512 + pos] = (short)f2b(val);
                }
            }
        }
        const size_t rc0 = (size_t)((m0 + wy * 64) >> 4);
        const size_t cc0 = (size_t)((n0 + wx * 64) >> 5);
        const size_t nch = (size_t)(N >> 5);
        #pragma unroll
        for (int c = 0; c < 8; ++c) {
            int raddr = lane * 8;
            raddr ^= ((raddr >> 7) & 3) << 3;
            s16x8 v = *((const s16x8*)&Wl[c * 512 + raddr]);
            size_t chunk = (rc0 + (c >> 1)) * nch + cc0 + (c & 1);
            *((s16x8*)&((unsigned short*)Cout)[chunk * 512 + lane * 8]) = v;
        }
    }
}

// ---- attention tile (QBLK=64, KVBLK=32 dbuf, Q-in-reg) — R10 body ----
__device__ void fattn_tile(int bid, char* SH,
                           const unsigned short* qkv, const unsigned short* Vt,
                           unsigned short* out) {
    short* Ks    = (short*)SH;          // 2 x 2048
    short* Vs    = Ks + 4096;           // 2 x 2048
    short* Ps    = Vs + 4096;           // 64*40
    short* OnesB = Ps + 2560;           // 512

    const int tid = threadIdx.x, lane = tid & 63, wave = tid >> 6;
    const int lr = lane & 15, lq = lane >> 4;
    const int L = bid;
    const int idx = L >> 3;
    const int qt = idx & 15;
    const int bh = (L & 7) + 8 * (idx >> 4);
    const int b = bh >> 4, h = bh & 15;
    const int q0 = qt * 64;

    __syncthreads();                    // SH handoff
    {
        s16x8 zz = (s16x8){0,0,0,0,0,0,0,0};
        if (lr == 0) { zz[0] = (short)0x3F80; zz[1] = (short)0x3F80;
                       zz[2] = (short)0x3F80; zz[3] = (short)0x3F80;
                       zz[4] = (short)0x3F80; zz[5] = (short)0x3F80;
                       zz[6] = (short)0x3F80; zz[7] = (short)0x3F80; }
        if (wave == 0) *((s16x8*)&OnesB[lane * 8]) = zz;
    }

    s16x8 aq[2];
    #pragma unroll
    for (int j = 0; j < 2; ++j) {
        const unsigned short* g = qkv + ((size_t)(((b * SEQ + q0) >> 4) + wave) * 96
                                         + 2 * h + j) * 512 + lane * 8;
        aq[j] = *((const s16x8*)g);
    }

    const unsigned short* kgb = qkv + ((size_t)(((b * SEQ) >> 4) + (wave >> 1)) * 96
                                       + 32 + 2 * h + (wave & 1)) * 512 + lane * 8;
    const unsigned short* vgb = Vt + (size_t)bh * 65536 + (size_t)wave * 32 * 512 + lane * 8;

    f32x4 osum[5];
    #pragma unroll
    for (int d = 0; d < 5; ++d)
        osum[d] = (f32x4){0.f, 0.f, 0.f, 0.f};

    const float c = 0.125f * 1.44269504f;

#define ASTG(buf, kt) { \
    gload_lds16(kgb + (size_t)(kt) * (2 * 96 * 512), &Ks[(buf) * 2048 + wave * 512]); \
    gload_lds16(vgb + (size_t)(kt) * 512, &Vs[(buf) * 2048 + wave * 512]); }

#define ACMP(buf) { \
    f32x4 s0 = (f32x4){0.f,0.f,0.f,0.f}, s1 = (f32x4){0.f,0.f,0.f,0.f}; \
    __builtin_amdgcn_s_setprio(1); \
    _Pragma("unroll") for (int kc_ = 0; kc_ < 2; ++kc_) { \
        s16x8 bk0 = *((const s16x8*)&Ks[(buf) * 2048 + (0 * 2 + kc_) * 512 + lane * 8]); \
        s16x8 bk1 = *((const s16x8*)&Ks[(buf) * 2048 + (1 * 2 + kc_) * 512 + lane * 8]); \
        s0 = __builtin_amdgcn_mfma_f32_16x16x32_bf16(aq[kc_], bk0, s0, 0, 0, 0); \
        s1 = __builtin_amdgcn_mfma_f32_16x16x32_bf16(aq[kc_], bk1, s1, 0, 0, 0); \
    } \
    __builtin_amdgcn_s_setprio(0); \
    _Pragma("unroll") for (int r_ = 0; r_ < 4; ++r_) { \
        int prow = wave * 16 + lq * 4 + r_; \
        Ps[prow * 40 + lr]      = (short)f2b(exp2f(s0[r_] * c)); \
        Ps[prow * 40 + 16 + lr] = (short)f2b(exp2f(s1[r_] * c)); \
    } \
    s16x8 ap = *((const s16x8*)&Ps[(wave * 16 + lr) * 40 + lq * 8]); \
    __builtin_amdgcn_s_setprio(1); \
    _Pragma("unroll") for (int db_ = 0; db_ < 4; ++db_) { \
        s16x8 bv = *((const s16x8*)&Vs[(buf) * 2048 + db_ * 512 + lane * 8]); \
        osum[db_] = __builtin_amdgcn_mfma_f32_16x16x32_bf16(ap, bv, osum[db_], 0, 0, 0); \
    } \
    osum[4] = __builtin_amdgcn_mfma_f32_16x16x32_bf16(ap, bo, osum[4], 0, 0, 0); \
    __builtin_amdgcn_s_setprio(0); }

    ASTG(0, 0);
    __syncthreads();
    s16x8 bo = *((const s16x8*)&OnesB[lane * 8]);

    for (int t = 0; t < 32; t += 2) {
        ASTG(1, t + 1);
        ACMP(0);
        __syncthreads();
        if (t + 2 < 32) ASTG(0, t + 2);
        ACMP(1);
        __syncthreads();
    }
#undef ASTG
#undef ACMP

    {
        int qrow = q0 + wave * 16 + lq * 4;
        #pragma unroll
        for (int r = 0; r < 4; ++r) {
            float lsum = __shfl(osum[4][r], lane & 48, 64);
            float inv = 1.0f / lsum;
            int row = b * SEQ + qrow + r;
            #pragma unroll
            for (int db = 0; db < 4; ++db)
                out[tidx(row, h * 64 + db * 16 + lr, DIM)] = f2b(osum[db][r] * inv);
        }
    }
}

// =================== the persistent mega kernel ===================
__global__ __launch_bounds__(256, 4) void mega(
        const float* x, const float* ln1_g, const float* ln1_b,
        const float* ln2_g, const float* ln2_b,
        const float* qkv_w, const float* qkv_b,
        const float* proj_w, const float* proj_b,
        const float* fc1_w, const float* fc1_b,
        const float* fc2_w, const float* fc2_b,
        float* out,
        unsigned short* wT_qkv, unsigned short* wT_proj,
        unsigned short* wT_fc1, unsigned short* wT_fc2,
        unsigned short* lnout, unsigned short* qkvbuf, unsigned short* Vt,
        unsigned short* attnout, unsigned short* gelu,
        unsigned short* pp0, unsigned short* pp1,
        unsigned short* fp0, unsigned short* fp1,
        unsigned short* fp2, unsigned short* fp3) {
    __shared__ __align__(16) char SH[32768];
    const int bid = blockIdx.x;

    // phase 0: prep (LN1 rows + weight converts), 7168 units
    for (int u = bid; u < ROWS + 3072; u += NBLK)
        prep_unit(u, SH, x, ln1_g, ln1_b, lnout,
                  qkv_w, wT_qkv, proj_w, wT_proj, fc1_w, wT_fc1, fc2_w, wT_fc2);
    gbar();
    // phase 1: qkv GEMM (768 tiles, fuse 0 + V scatter)
    if (bid < 768)
        gemm_tile(lnout, wT_qkv, qkv_b, qkvbuf, Vt, nullptr, nullptr, nullptr, nullptr,
                  3 * DIM, DIM, DIM, 0, bid, 32, 24, 0, SH);
    gbar();
    // phase 2: flash attention (1024 tiles)
    fattn_tile(bid, SH, qkvbuf, Vt, attnout);
    gbar();
    // phase 3: proj split-K S=2 (512 tiles, fuse 3)
    if (bid < 512)
        gemm_tile(attnout, wT_proj, proj_b, nullptr, nullptr, pp0, pp1, nullptr, nullptr,
                  DIM, DIM, DIM / 2, 3, bid & 255, 32, 8, bid >> 8, SH);
    gbar();
    // phase 4: x1 = x + proj partials + proj_b -> out; LN2 -> lnout (4096 rows)
    for (int r = bid; r < ROWS; r += NBLK)
        reduce_ln_unit(r, SH, pp0, pp1, x, proj_b, ln2_g, ln2_b, out, lnout);
    gbar();
    // phase 5: fc1 GEMM + GELU (1024 tiles, fuse 1)
    gemm_tile(lnout, wT_fc1, fc1_b, gelu, nullptr, nullptr, nullptr, nullptr, nullptr,
              HIDDEN, DIM, DIM, 1, bid, 32, 32, 0, SH);
    gbar();
    // phase 6: fc2 split-K S=4 (1024 tiles, fuse 3)
    gemm_tile(gelu, wT_fc2, fc2_b, nullptr, nullptr, fp0, fp1, fp2, fp3,
              DIM, HIDDEN, HIDDEN / 4, 3, bid & 255, 32, 8, bid >> 8, SH);
    gbar();
    // phase 7: out = x1 + fc2 partials + fc2_b (2048 units)
    for (int u = bid; u < 2048; u += NBLK)
        reduce_unit(u, fp0, fp1, fp2, fp3, out, fc2_b, out);
}

extern "C" void kernel_launch(void* const* d_in, const int* in_sizes, int n_in,
                              void* d_out, int out_size, void* d_ws, size_t ws_size,
                              hipStream_t stream) {
    const float* x      = (const float*)d_in[0];
    const float* ln1_g  = (const float*)d_in[1];
    const float* ln1_b  = (const float*)d_in[2];
    const float* ln2_g  = (const float*)d_in[3];
    const float* ln2_b  = (const float*)d_in[4];
    const float* qkv_w  = (const float*)d_in[5];
    const float* qkv_b  = (const float*)d_in[6];
    const float* proj_w = (const float*)d_in[7];
    const float* proj_b = (const float*)d_in[8];
    const float* fc1_w  = (const float*)d_in[9];
    const float* fc1_b  = (const float*)d_in[10];
    const float* fc2_w  = (const float*)d_in[11];
    const float* fc2_b  = (const float*)d_in[12];
    float* out = (float*)d_out;

    // workspace layout (MiB), 72 total — liveness-packed (same as R10)
    char* ws = (char*)d_ws;
    unsigned short* wT_fc2  = (unsigned short*)(ws);
    unsigned short* wT_qkv  = (unsigned short*)(ws + (8u  << 20));
    unsigned short* wT_proj = (unsigned short*)(ws + (14u << 20));
    unsigned short* qkvbuf  = (unsigned short*)(ws + (16u << 20));
    unsigned short* Vt      = (unsigned short*)(ws + (40u << 20));
    unsigned short* attnout = (unsigned short*)(ws + (48u << 20));
    unsigned short* lnout   = (unsigned short*)(ws + (56u << 20));
    unsigned short* wT_fc1  = (unsigned short*)(ws + (64u << 20));
    unsigned short* gelu    = (unsigned short*)(ws + (16u << 20));
    unsigned short* pp0 = (unsigned short*)(ws + (16u << 20));
    unsigned short* pp1 = (unsigned short*)(ws + (24u << 20));
    unsigned short* fp0 = (unsigned short*)(ws + (48u << 20));
    unsigned short* fp1 = (unsigned short*)(ws + (56u << 20));
    unsigned short* fp2 = (unsigned short*)(ws + (64u << 20));
    unsigned short* fp3 = (unsigned short*)(ws + (8u  << 20));

    mega<<<NBLK, 256, 0, stream>>>(
        x, ln1_g, ln1_b, ln2_g, ln2_b,
        qkv_w, qkv_b, proj_w, proj_b, fc1_w, fc1_b, fc2_w, fc2_b,
        out,
        wT_qkv, wT_proj, wT_fc1, wT_fc2,
        lnout, qkvbuf, Vt, attnout, gelu,
        pp0, pp1, fp0, fp1, fp2, fp3);
}